// Round 16
// baseline (94.342 us; speedup 1.0000x reference)
//
#include <hip/hip_runtime.h>
#include <hip/hip_bf16.h>

typedef float f32x4 __attribute__((ext_vector_type(4)));
typedef short s16x8 __attribute__((ext_vector_type(8)));
typedef unsigned int u32;
typedef u32 u32x2 __attribute__((ext_vector_type(2)));

#define DIST_SCALE 25.0f

__device__ __forceinline__ unsigned short f2b(float f) {
  union { float f; unsigned u; } v; v.f = f;
  unsigned r = v.u + 0x7fffu + ((v.u >> 16) & 1u);
  return (unsigned short)(r >> 16);
}

__device__ __forceinline__ u32 cvtpk(float lo, float hi) {
  u32 r;
  asm("v_cvt_pk_bf16_f32 %0, %1, %2" : "=v"(r) : "v"(lo), "v"(hi));
  return r;
}

// HA: [64 samples][128 ch] bf16, 256B rows, XOR-swizzled
__device__ __forceinline__ int swzH(int s, int chbyte) {
  return (s * 256 + chbyte) ^ ((s & 7) << 4);
}

__global__ void prep_weights(const float* __restrict__ W1, const float* __restrict__ W2,
                             const float* __restrict__ W3, unsigned short* __restrict__ ws) {
  int t = blockIdx.x * 256 + threadIdx.x;
  int stride = gridDim.x * 256;
  // W1aT[n][k] (k padded 27->32 with ZEROS - annihilates X tail garbage)
  for (int i = t; i < 128 * 32; i += stride) {
    int n = i >> 5, k = i & 31;
    ws[i] = (k < 27) ? f2b(W1[k * 128 + n]) : (unsigned short)0;
  }
  unsigned short* w2t = ws + 4096;
  for (int i = t; i < 128 * 128; i += stride) {
    int n = i >> 7, k = i & 127;
    w2t[i] = f2b(W2[k * 128 + n]);
  }
  // W3P[wv(4)][n(16)][kslot(32)]: k-slot (kg,j) -> ch = wv*32 + 16*(j>>2) + kg*4 + (j&3)
  unsigned short* w3p = ws + 4096 + 16384;
  for (int i = t; i < 4 * 16 * 32; i += stride) {
    int wv = i >> 9, rem = i & 511, n = rem >> 5, ks = rem & 31;
    int kg = ks >> 3, j = ks & 7;
    int ch = wv * 32 + ((j >> 2) << 4) + kg * 4 + (j & 3);
    w3p[i] = (n < 3) ? f2b(W3[ch * 3 + n]) : (unsigned short)0;
  }
}

__global__ void __launch_bounds__(256, 3) nerf_main(
    const float* __restrict__ dens, const float* __restrict__ app,
    const float* __restrict__ vdirs, const float* __restrict__ dists,
    const float* __restrict__ W1, const float* __restrict__ b1,
    const float* __restrict__ b2v, const float* __restrict__ b3v,
    const unsigned short* __restrict__ wsb, float* __restrict__ out) {
  __shared__ unsigned short HA[64 * 128];        // 16 KB H1 activations [s][ch]
  __shared__ __align__(16) float pool[768];      // 3 KB: prologue {feat[0..39], hc[64..191]};
                                                 //       loop: part[64 s][3 c][4 src]
  __shared__ float wbuf[256];
  __shared__ float red[4][4];

  const int t = threadIdx.x;
  const int lane = t & 63;
  const int wv = t >> 6;
  const int r = blockIdx.x;

  const unsigned short* W1aT = wsb;
  const unsigned short* W2T = wsb + 4096;
  const unsigned short* W3P = wsb + 4096 + 16384;
  char* HAb = (char*)HA;

  const int cl = lane & 15;    // A-row / C-col index
  const int kg = lane >> 4;    // k-group; C rows = kg*4+i
  const int chBase = wv * 32;  // this wave's output-channel slice
  float* featbuf = pool;
  float* hcbuf = pool + 64;

  // ---------------- prologue ----------------
  if (t < 39) {   // view-dir features: [vd(3), sin(18), cos(18)]
    float val;
    if (t < 3) val = vdirs[r * 3 + t];
    else {
      int jj = t - 3;
      int trig = jj / 18;
      int rem = jj % 18;
      int c = rem / 6, k = rem % 6;
      float v = vdirs[r * 3 + c] * (float)(1 << k);
      val = trig ? cosf(v) : sinf(v);
    }
    featbuf[t] = val;
  }
  // transmittance/weight scan (wave 0, 4 samples/lane)
  if (wv == 0) {
    const float4 dv = *(const float4*)(dens + (size_t)r * 256 + lane * 4);
    const float4 tv = *(const float4*)(dists + (size_t)r * 256 + lane * 4);
    float f[4], al[4];
    float dl[4] = {dv.x, dv.y, dv.z, dv.w};
    float tl[4] = {tv.x, tv.y, tv.z, tv.w};
    float p = 1.0f;
#pragma unroll
    for (int q = 0; q < 4; ++q) {
      float sg = fmaxf(dl[q], 0.0f);
      float e = __expf(-sg * tl[q] * DIST_SCALE);
      al[q] = 1.0f - e;
      f[q] = e + 1e-10f;
      p *= f[q];
    }
    float P = p;
#pragma unroll
    for (int dlt = 1; dlt < 64; dlt <<= 1) {
      float v = __shfl_up(P, dlt, 64);
      if (lane >= dlt) P *= v;
    }
    float E = __shfl_up(P, 1, 64);
    if (lane == 0) E = 1.0f;
    float tr = E;
#pragma unroll
    for (int q = 0; q < 4; ++q) { wbuf[lane * 4 + q] = al[q] * tr; tr *= f[q]; }
  }
  __syncthreads();
  // per-ray folded layer-1 bias: h1c = b1 + vd_feats @ W1[27:66]
  if (t < 128) {
    float s = b1[t];
    for (int j = 0; j < 39; ++j) s += featbuf[j] * W1[(27 + j) * 128 + t];
    hcbuf[t] = s;
  }

  // ---- hoist this wave's weight slice into registers (one-time, 44 VGPR) ----
  s16x8 w1f[2], w2f[2][4], w3s;
#pragma unroll
  for (int nt = 0; nt < 2; ++nt)
    w1f[nt] = *(const s16x8*)(W1aT + (chBase + nt * 16 + cl) * 32 + kg * 8);
#pragma unroll
  for (int nt = 0; nt < 2; ++nt)
#pragma unroll
    for (int kk = 0; kk < 4; ++kk)
      w2f[nt][kk] = *(const s16x8*)(W2T + (chBase + nt * 16 + cl) * 128 + kk * 32 + kg * 8);
  w3s = *(const s16x8*)(W3P + wv * 512 + cl * 32 + kg * 8);

  __syncthreads();   // hcbuf written block-wide; after this barrier pool becomes `part`
  // chunk-invariant bias vectors read BEFORE any wave can write part (fenced by first B2)
  const f32x4 hc0 = *(const f32x4*)(hcbuf + chBase + kg * 4);
  const f32x4 hc1 = *(const f32x4*)(hcbuf + chBase + 16 + kg * 4);
  const f32x4 bb0 = *(const f32x4*)(b2v + chBase + kg * 4);
  const f32x4 bb1 = *(const f32x4*)(b2v + chBase + 16 + kg * 4);
  const float b3c = (kg < 3) ? b3v[kg] : 0.0f;
  float pacc = 0.0f;
  float* part = pool;

  const float* rayBase = app + (size_t)r * 6912;

  for (int chunk = 0; chunk < 4; ++chunk) {
    const int sBase = chunk * 64;
    const float* ckBase = rayBase + chunk * 1728;
    const bool tailCk = (r == 4095) && (chunk == 3);

    // ---- layer 1: X frags straight from global (per-lane 32B), acc init = bias ----
#pragma unroll
    for (int st = 0; st < 4; ++st) {
      const int s = st * 16 + cl;
      const float* gp = ckBase + s * 27 + kg * 8;
      f32x4 va, vb;
      if (__builtin_expect(tailCk && st == 3, 0)) {
        if (kg == 3 && cl == 15) {   // last 3 floats of the whole buffer; rest zero
          va = (f32x4){gp[0], gp[1], gp[2], 0.0f};
          vb = (f32x4){0.0f, 0.0f, 0.0f, 0.0f};
        } else {
          va = *(const f32x4*)gp;
          vb = *(const f32x4*)(gp + 4);
        }
      } else {
        va = *(const f32x4*)gp;
        vb = *(const f32x4*)(gp + 4);
      }
      union { u32 u[4]; s16x8 v; } xb;
      xb.u[0] = cvtpk(va[0], va[1]);
      xb.u[1] = cvtpk(va[2], va[3]);
      xb.u[2] = cvtpk(vb[0], vb[1]);
      xb.u[3] = cvtpk(vb[2], vb[3]);   // k>=27 garbage killed by W1aT zero cols
      f32x4 a0 = hc0, a1 = hc1;
      a0 = __builtin_amdgcn_mfma_f32_16x16x32_bf16(w1f[0], xb.v, a0, 0, 0, 0);
      a1 = __builtin_amdgcn_mfma_f32_16x16x32_bf16(w1f[1], xb.v, a1, 0, 0, 0);
      u32x2 pk0 = {cvtpk(fmaxf(a0[0], 0.0f), fmaxf(a0[1], 0.0f)),
                   cvtpk(fmaxf(a0[2], 0.0f), fmaxf(a0[3], 0.0f))};
      u32x2 pk1 = {cvtpk(fmaxf(a1[0], 0.0f), fmaxf(a1[1], 0.0f)),
                   cvtpk(fmaxf(a1[2], 0.0f), fmaxf(a1[3], 0.0f))};
      *(u32x2*)(HAb + swzH(s, (chBase + kg * 4) * 2)) = pk0;
      *(u32x2*)(HAb + swzH(s, (chBase + 16 + kg * 4) * 2)) = pk1;
    }
    __syncthreads();   // B2: H1 ready; prev-chunk part reads done (they precede this barrier)

    // ---- layer 2 (acc init = b2) + fused layer-3 partial (B3-op = own relu'd acc regs) ----
#pragma unroll
    for (int st = 0; st < 4; ++st) {
      const int s = st * 16 + cl;
      s16x8 hbf[4];
#pragma unroll
      for (int kk = 0; kk < 4; ++kk)
        hbf[kk] = *(const s16x8*)(HAb + swzH(s, (kk * 32 + kg * 8) * 2));
      f32x4 a0 = bb0, a1 = bb1;
#pragma unroll
      for (int kk = 0; kk < 4; ++kk) {
        a0 = __builtin_amdgcn_mfma_f32_16x16x32_bf16(w2f[0][kk], hbf[kk], a0, 0, 0, 0);
        a1 = __builtin_amdgcn_mfma_f32_16x16x32_bf16(w2f[1][kk], hbf[kk], a1, 0, 0, 0);
      }
      union { u32 u[4]; s16x8 v; } b3;
      b3.u[0] = cvtpk(fmaxf(a0[0], 0.0f), fmaxf(a0[1], 0.0f));
      b3.u[1] = cvtpk(fmaxf(a0[2], 0.0f), fmaxf(a0[3], 0.0f));
      b3.u[2] = cvtpk(fmaxf(a1[0], 0.0f), fmaxf(a1[1], 0.0f));
      b3.u[3] = cvtpk(fmaxf(a1[2], 0.0f), fmaxf(a1[3], 0.0f));
      f32x4 p3 = {};
      p3 = __builtin_amdgcn_mfma_f32_16x16x32_bf16(w3s, b3.v, p3, 0, 0, 0);
      if (kg == 0) {   // rgb rows 0..2 of this wave's K-partial -> part[s][c][wv]
        float* pp = part + s * 12;
        pp[wv] = p3[0];
        pp[4 + wv] = p3[1];
        pp[8 + wv] = p3[2];
      }
    }
    __syncthreads();   // B3: partials written; HA reads done (next L1 HA-writes safe)

    // ---- composite: lane (cl,kg) owns (sample wv*16+cl, color kg); kg==3 owns acc_map ----
    {
      const int s = wv * 16 + cl;
      const float w = wbuf[sBase + s];
      if (kg < 3) {
        f32x4 pv = *(const f32x4*)(part + s * 12 + kg * 4);   // 4 src partials of color kg
        float v = (pv[0] + pv[1]) + (pv[2] + pv[3]) + b3c;
        pacc += w / (1.0f + __expf(-v));
      } else {
        pacc += w;   // acc_map
      }
    }
    // part rewrite (next chunk, post-B2) fenced vs these reads by next B2
  }

  // ---------------- final reduce + composite ----------------
#pragma unroll
  for (int d = 1; d < 16; d <<= 1) pacc += __shfl_xor(pacc, d, 64);
  if (cl == 0) red[wv][kg] = pacc;   // lanes 0,16,32,48 hold color kg totals of this wave
  __syncthreads();
  if (t == 0) {
    float R = red[0][0] + red[1][0] + red[2][0] + red[3][0];
    float G = red[0][1] + red[1][1] + red[2][1] + red[3][1];
    float B = red[0][2] + red[1][2] + red[2][2] + red[3][2];
    float W = red[0][3] + red[1][3] + red[2][3] + red[3][3];
    float bg = 1.0f - W;
    out[r * 3 + 0] = fminf(fmaxf(R + bg, 0.0f), 1.0f);
    out[r * 3 + 1] = fminf(fmaxf(G + bg, 0.0f), 1.0f);
    out[r * 3 + 2] = fminf(fmaxf(B + bg, 0.0f), 1.0f);
  }
}

extern "C" void kernel_launch(void* const* d_in, const int* in_sizes, int n_in,
                              void* d_out, int out_size, void* d_ws, size_t ws_size,
                              hipStream_t stream) {
  const float* dens = (const float*)d_in[0];
  const float* app  = (const float*)d_in[1];
  const float* vd   = (const float*)d_in[2];
  const float* dist = (const float*)d_in[3];
  const float* W1   = (const float*)d_in[4];
  const float* b1   = (const float*)d_in[5];
  const float* W2   = (const float*)d_in[6];
  const float* b2   = (const float*)d_in[7];
  const float* W3   = (const float*)d_in[8];
  const float* b3   = (const float*)d_in[9];
  unsigned short* wsb = (unsigned short*)d_ws;

  prep_weights<<<32, 256, 0, stream>>>(W1, W2, W3, wsb);
  nerf_main<<<4096, 256, 0, stream>>>(dens, app, vd, dist, W1, b1, b2, b3, wsb, (float*)d_out);
}

// Round 17
// 77.495 us; speedup vs baseline: 1.2174x; 1.2174x over previous
//
#include <hip/hip_runtime.h>
#include <hip/hip_bf16.h>

typedef float f32x4 __attribute__((ext_vector_type(4)));
typedef short s16x8 __attribute__((ext_vector_type(8)));
typedef unsigned int u32;
typedef u32 u32x2 __attribute__((ext_vector_type(2)));

#define DIST_SCALE 25.0f

__device__ __forceinline__ unsigned short f2b(float f) {
  union { float f; unsigned u; } v; v.f = f;
  unsigned r = v.u + 0x7fffu + ((v.u >> 16) & 1u);
  return (unsigned short)(r >> 16);
}

__device__ __forceinline__ u32 cvtpk(float lo, float hi) {
  u32 r;
  asm("v_cvt_pk_bf16_f32 %0, %1, %2" : "=v"(r) : "v"(lo), "v"(hi));
  return r;
}

// HA buffer: [64 samples][128 ch] bf16, 256B rows, XOR-swizzled
__device__ __forceinline__ int swzH(int s, int chbyte) {
  return (s * 256 + chbyte) ^ ((s & 7) << 4);
}

__global__ void prep_weights(const float* __restrict__ W1, const float* __restrict__ W2,
                             const float* __restrict__ W3, unsigned short* __restrict__ ws) {
  int t = blockIdx.x * 256 + threadIdx.x;
  int stride = gridDim.x * 256;
  // W1aT[n][k] (k padded 27->32 with ZEROS - annihilates X tail garbage)
  for (int i = t; i < 128 * 32; i += stride) {
    int n = i >> 5, k = i & 31;
    ws[i] = (k < 27) ? f2b(W1[k * 128 + n]) : (unsigned short)0;
  }
  unsigned short* w2t = ws + 4096;
  for (int i = t; i < 128 * 128; i += stride) {
    int n = i >> 7, k = i & 127;
    w2t[i] = f2b(W2[k * 128 + n]);
  }
  // W3P[wv(4)][n(16)][kslot(32)]: k-slot (kg,j) -> ch = wv*32 + 16*(j>>2) + kg*4 + (j&3)
  unsigned short* w3p = ws + 4096 + 16384;
  for (int i = t; i < 4 * 16 * 32; i += stride) {
    int wv = i >> 9, rem = i & 511, n = rem >> 5, ks = rem & 31;
    int kg = ks >> 3, j = ks & 7;
    int ch = wv * 32 + ((j >> 2) << 4) + kg * 4 + (j & 3);
    w3p[i] = (n < 3) ? f2b(W3[ch * 3 + n]) : (unsigned short)0;
  }
}

__global__ void __launch_bounds__(256) nerf_main(
    const float* __restrict__ dens, const float* __restrict__ app,
    const float* __restrict__ vdirs, const float* __restrict__ dists,
    const float* __restrict__ W1, const float* __restrict__ b1,
    const float* __restrict__ b2v, const float* __restrict__ b3v,
    const unsigned short* __restrict__ wsb, float* __restrict__ out) {
  __shared__ unsigned short HA[2][64 * 128];     // 32 KB double-buffered H1 [s][ch]
  __shared__ __align__(16) float part[2][64 * 12];  // 6 KB C3 partials [s][c(3)][src(4)]
  __shared__ float wbuf[256];
  __shared__ float hcbuf[128];
  __shared__ float featbuf[40];
  __shared__ float red[4][4];

  const int t = threadIdx.x;
  const int lane = t & 63;
  const int wv = t >> 6;
  const int r = blockIdx.x;

  const unsigned short* W1aT = wsb;
  const unsigned short* W2T = wsb + 4096;
  const unsigned short* W3P = wsb + 4096 + 16384;

  const int cl = lane & 15;    // sample-in-tile for L1 C / A-row for L2
  const int kg = lane >> 4;    // k-group
  const int chBase = wv * 32;  // L2: this wave's output-channel slice
  const int myS = wv * 16 + cl;  // L1/composite: this lane's sample within chunk

  const float* rayBase = app + (size_t)r * 6912;

  // ---- prefetch chunk 0 X straight into registers (hidden under prologue) ----
  // lane (cl,kg) of wave wv needs X[s=wv*16+cl][k=kg*8 .. +7]
  f32x4 va, vb;
  {
    const float* gp = rayBase + myS * 27 + kg * 8;
    va = *(const f32x4*)gp;
    vb = *(const f32x4*)(gp + 4);
  }

  // ---------------- prologue ----------------
  if (t < 39) {   // view-dir features: [vd(3), sin(18), cos(18)]
    float val;
    if (t < 3) val = vdirs[r * 3 + t];
    else {
      int jj = t - 3;
      int trig = jj / 18;
      int rem = jj % 18;
      int c = rem / 6, k = rem % 6;
      float v = vdirs[r * 3 + c] * (float)(1 << k);
      val = trig ? cosf(v) : sinf(v);
    }
    featbuf[t] = val;
  }
  // transmittance/weight scan (wave 0, 4 samples/lane)
  if (wv == 0) {
    const float4 dv = *(const float4*)(dens + (size_t)r * 256 + lane * 4);
    const float4 tv = *(const float4*)(dists + (size_t)r * 256 + lane * 4);
    float f[4], al[4];
    float dl[4] = {dv.x, dv.y, dv.z, dv.w};
    float tl[4] = {tv.x, tv.y, tv.z, tv.w};
    float p = 1.0f;
#pragma unroll
    for (int q = 0; q < 4; ++q) {
      float sg = fmaxf(dl[q], 0.0f);
      float e = __expf(-sg * tl[q] * DIST_SCALE);
      al[q] = 1.0f - e;
      f[q] = e + 1e-10f;
      p *= f[q];
    }
    float P = p;
#pragma unroll
    for (int dlt = 1; dlt < 64; dlt <<= 1) {
      float v = __shfl_up(P, dlt, 64);
      if (lane >= dlt) P *= v;
    }
    float E = __shfl_up(P, 1, 64);
    if (lane == 0) E = 1.0f;
    float tr = E;
#pragma unroll
    for (int q = 0; q < 4; ++q) { wbuf[lane * 4 + q] = al[q] * tr; tr *= f[q]; }
  }
  __syncthreads();
  // per-ray folded layer-1 bias: h1c = b1 + vd_feats @ W1[27:66]
  if (t < 128) {
    float s = b1[t];
    for (int j = 0; j < 39; ++j) s += featbuf[j] * W1[(27 + j) * 128 + t];
    hcbuf[t] = s;
  }

  // ---- hoist weights: L1 A-frags for ALL 128 ch (32 VGPR) + L2 slice (32) + W3P (4) ----
  s16x8 w1f[8], w2f[2][4], w3s;
#pragma unroll
  for (int nt = 0; nt < 8; ++nt)
    w1f[nt] = *(const s16x8*)(W1aT + (nt * 16 + cl) * 32 + kg * 8);
#pragma unroll
  for (int nt = 0; nt < 2; ++nt)
#pragma unroll
    for (int kk = 0; kk < 4; ++kk)
      w2f[nt][kk] = *(const s16x8*)(W2T + (chBase + nt * 16 + cl) * 128 + kk * 32 + kg * 8);
  w3s = *(const s16x8*)(W3P + wv * 512 + cl * 32 + kg * 8);

  const f32x4 bb0 = *(const f32x4*)(b2v + chBase + kg * 4);
  const f32x4 bb1 = *(const f32x4*)(b2v + chBase + 16 + kg * 4);
  const float b30 = b3v[0], b31 = b3v[1], b32 = b3v[2];
  const float b3c = (kg < 3) ? b3v[kg] : 0.0f;
  float pacc = 0.0f;

  __syncthreads();   // hcbuf ready (read in L1 epilogue every iter)

  for (int chunk = 0; chunk < 4; ++chunk) {
    char* HAc = (char*)HA[chunk & 1];

    // ---- layer 1: wave's 16 samples x all 128 ch; B-frag from own prefetched regs ----
    {
      union { u32 u[4]; s16x8 v; } xb;
      xb.u[0] = cvtpk(va[0], va[1]);
      xb.u[1] = cvtpk(va[2], va[3]);
      xb.u[2] = cvtpk(vb[0], vb[1]);
      xb.u[3] = cvtpk(vb[2], vb[3]);   // k>=27 garbage killed by W1aT zero cols
#pragma unroll
      for (int nt = 0; nt < 8; ++nt) {
        f32x4 hcf = *(const f32x4*)(hcbuf + nt * 16 + kg * 4);   // broadcast read
        f32x4 a = hcf;
        a = __builtin_amdgcn_mfma_f32_16x16x32_bf16(w1f[nt], xb.v, a, 0, 0, 0);
        // C: lane(cl,kg) reg i -> ch = nt*16+kg*4+i, sample = wv*16+cl (wave-private row)
        u32x2 pk = {cvtpk(fmaxf(a[0], 0.0f), fmaxf(a[1], 0.0f)),
                    cvtpk(fmaxf(a[2], 0.0f), fmaxf(a[3], 0.0f))};
        *(u32x2*)(HAc + swzH(myS, (nt * 16 + kg * 4) * 2)) = pk;
      }
    }

    // ---- prefetch next chunk's X into regs (latency spans the barrier + L2 phase) ----
    if (chunk < 3) {
      const float* gp = rayBase + (chunk + 1) * 1728 + myS * 27 + kg * 8;
      if (__builtin_expect(r == 4095 && chunk == 2 && myS == 63 && kg == 3, 0)) {
        va = (f32x4){gp[0], gp[1], gp[2], 0.0f};   // last 3 floats of whole buffer
        vb = (f32x4){0.0f, 0.0f, 0.0f, 0.0f};
      } else {
        va = *(const f32x4*)gp;
        vb = *(const f32x4*)(gp + 4);
      }
    }

    __syncthreads();   // B1: HA[chunk&1] complete; part[(chunk-1)&1] writes visible

    // ---- deferred composite of previous chunk (overlaps other waves' L2 entry) ----
    if (chunk > 0) {
      const float w = wbuf[(chunk - 1) * 64 + myS];
      if (kg < 3) {
        f32x4 pv = *(const f32x4*)(part[(chunk - 1) & 1] + myS * 12 + kg * 4);
        float v = (pv[0] + pv[1]) + (pv[2] + pv[3]) + b3c;
        pacc += w / (1.0f + __expf(-v));
      } else {
        pacc += w;   // acc_map
      }
    }

    // ---- layer 2 (acc init = b2) + fused layer-3 partial (B3-op = own relu'd acc regs) ----
#pragma unroll
    for (int st = 0; st < 4; ++st) {
      const int s = st * 16 + cl;
      s16x8 hbf[4];
#pragma unroll
      for (int kk = 0; kk < 4; ++kk)
        hbf[kk] = *(const s16x8*)(HAc + swzH(s, (kk * 32 + kg * 8) * 2));
      f32x4 a0 = bb0, a1 = bb1;
#pragma unroll
      for (int kk = 0; kk < 4; ++kk) {
        a0 = __builtin_amdgcn_mfma_f32_16x16x32_bf16(w2f[0][kk], hbf[kk], a0, 0, 0, 0);
        a1 = __builtin_amdgcn_mfma_f32_16x16x32_bf16(w2f[1][kk], hbf[kk], a1, 0, 0, 0);
      }
      union { u32 u[4]; s16x8 v; } b3;
      b3.u[0] = cvtpk(fmaxf(a0[0], 0.0f), fmaxf(a0[1], 0.0f));
      b3.u[1] = cvtpk(fmaxf(a0[2], 0.0f), fmaxf(a0[3], 0.0f));
      b3.u[2] = cvtpk(fmaxf(a1[0], 0.0f), fmaxf(a1[1], 0.0f));
      b3.u[3] = cvtpk(fmaxf(a1[2], 0.0f), fmaxf(a1[3], 0.0f));
      f32x4 p3 = {};
      p3 = __builtin_amdgcn_mfma_f32_16x16x32_bf16(w3s, b3.v, p3, 0, 0, 0);
      if (kg == 0) {   // rgb rows 0..2 -> part[chunk&1][s][c][wv]
        float* pp = part[chunk & 1] + s * 12;
        pp[wv] = p3[0];
        pp[4 + wv] = p3[1];
        pp[8 + wv] = p3[2];
      }
    }
    // no trailing barrier: next iter's L1 writes HA[other]; next B1 fences part
  }

  // ---------------- final chunk's composite + reduce ----------------
  __syncthreads();   // part[1] (chunk 3) writes visible
  {
    const float w = wbuf[3 * 64 + myS];
    if (kg < 3) {
      f32x4 pv = *(const f32x4*)(part[1] + myS * 12 + kg * 4);
      float v = (pv[0] + pv[1]) + (pv[2] + pv[3]) + b3c;
      pacc += w / (1.0f + __expf(-v));
    } else {
      pacc += w;
    }
  }
#pragma unroll
  for (int d = 1; d < 16; d <<= 1) pacc += __shfl_xor(pacc, d, 64);
  if (cl == 0) red[wv][kg] = pacc;   // lanes 0,16,32,48: color kg totals of this wave
  __syncthreads();
  if (t == 0) {
    float R = red[0][0] + red[1][0] + red[2][0] + red[3][0];
    float G = red[0][1] + red[1][1] + red[2][1] + red[3][1];
    float B = red[0][2] + red[1][2] + red[2][2] + red[3][2];
    float W = red[0][3] + red[1][3] + red[2][3] + red[3][3];
    float bg = 1.0f - W;
    out[r * 3 + 0] = fminf(fmaxf(R + bg, 0.0f), 1.0f);
    out[r * 3 + 1] = fminf(fmaxf(G + bg, 0.0f), 1.0f);
    out[r * 3 + 2] = fminf(fmaxf(B + bg, 0.0f), 1.0f);
  }
}

extern "C" void kernel_launch(void* const* d_in, const int* in_sizes, int n_in,
                              void* d_out, int out_size, void* d_ws, size_t ws_size,
                              hipStream_t stream) {
  const float* dens = (const float*)d_in[0];
  const float* app  = (const float*)d_in[1];
  const float* vd   = (const float*)d_in[2];
  const float* dist = (const float*)d_in[3];
  const float* W1   = (const float*)d_in[4];
  const float* b1   = (const float*)d_in[5];
  const float* W2   = (const float*)d_in[6];
  const float* b2   = (const float*)d_in[7];
  const float* W3   = (const float*)d_in[8];
  const float* b3   = (const float*)d_in[9];
  unsigned short* wsb = (unsigned short*)d_ws;

  prep_weights<<<32, 256, 0, stream>>>(W1, W2, W3, wsb);
  nerf_main<<<4096, 256, 0, stream>>>(dens, app, vd, dist, W1, b1, b2, b3, wsb, (float*)d_out);
}

// Round 19
// 77.284 us; speedup vs baseline: 1.2207x; 1.0027x over previous
//
#include <hip/hip_runtime.h>
#include <hip/hip_bf16.h>

typedef float f32x4 __attribute__((ext_vector_type(4)));
typedef short s16x8 __attribute__((ext_vector_type(8)));
typedef unsigned int u32;
typedef u32 u32x2 __attribute__((ext_vector_type(2)));

#define DIST_SCALE 25.0f

__device__ __forceinline__ unsigned short f2b(float f) {
  union { float f; unsigned u; } v; v.f = f;
  unsigned r = v.u + 0x7fffu + ((v.u >> 16) & 1u);
  return (unsigned short)(r >> 16);
}

__device__ __forceinline__ u32 cvtpk(float lo, float hi) {
  u32 r;
  asm("v_cvt_pk_bf16_f32 %0, %1, %2" : "=v"(r) : "v"(lo), "v"(hi));
  return r;
}

__global__ void prep_weights(const float* __restrict__ W1, const float* __restrict__ W2,
                             const float* __restrict__ W3, unsigned short* __restrict__ ws) {
  int t = blockIdx.x * 256 + threadIdx.x;
  int stride = gridDim.x * 256;
  // W1aT[n][k] (k padded 27->32 with ZEROS - annihilates X tail garbage)
  for (int i = t; i < 128 * 32; i += stride) {
    int n = i >> 5, k = i & 31;
    ws[i] = (k < 27) ? f2b(W1[k * 128 + n]) : (unsigned short)0;
  }
  unsigned short* w2t = ws + 4096;
  for (int i = t; i < 128 * 128; i += stride) {
    int n = i >> 7, k = i & 127;
    w2t[i] = f2b(W2[k * 128 + n]);
  }
  // W3P[wv(4)][n(16)][kslot(32)]: k-slot (kg,j) -> ch = wv*32 + 16*(j>>2) + kg*4 + (j&3)
  unsigned short* w3p = ws + 4096 + 16384;
  for (int i = t; i < 4 * 16 * 32; i += stride) {
    int wv = i >> 9, rem = i & 511, n = rem >> 5, ks = rem & 31;
    int kg = ks >> 3, j = ks & 7;
    int ch = wv * 32 + ((j >> 2) << 4) + kg * 4 + (j & 3);
    w3p[i] = (n < 3) ? f2b(W3[ch * 3 + n]) : (unsigned short)0;
  }
}

__global__ void __launch_bounds__(256) nerf_main(
    const float* __restrict__ dens, const float* __restrict__ app,
    const float* __restrict__ vdirs, const float* __restrict__ dists,
    const float* __restrict__ W1, const float* __restrict__ b1,
    const float* __restrict__ b2v, const float* __restrict__ b3v,
    const unsigned short* __restrict__ wsb, float* __restrict__ out) {
  __shared__ unsigned short HA[2 * 64 * 128];    // 32 KB dbuf H1; buf1 at byte +16384
  __shared__ __align__(16) float part[2 * 64 * 12];  // 6 KB C3 partials; buf1 at +3072 B
  __shared__ float wbuf[256];
  __shared__ float hcbuf[128];
  __shared__ float featbuf[40];
  __shared__ float red[4][4];

  const int t = threadIdx.x;
  const int lane = t & 63;
  const int wv = t >> 6;
  const int r = blockIdx.x;

  const unsigned short* W1aT = wsb;
  const unsigned short* W2T = wsb + 4096;
  const unsigned short* W3P = wsb + 4096 + 16384;
  char* HAb = (char*)HA;
  char* partB = (char*)part;
  char* hcB = (char*)hcbuf;

  const int cl = lane & 15;      // sample-in-tile for L1 C / A-row for L2
  const int kg = lane >> 4;      // k-group
  const int chBase = wv * 32;    // L2: this wave's output-channel slice
  const int myS = wv * 16 + cl;  // L1/composite: this lane's sample within chunk

  const float* rayBase = app + (size_t)r * 6912;

  // ---- prefetch chunk 0 X straight into registers (hidden under prologue) ----
  f32x4 va, vb;
  {
    const float* gp = rayBase + myS * 27 + kg * 8;
    va = *(const f32x4*)gp;
    vb = *(const f32x4*)(gp + 4);
  }

  // ---- hoisted LDS byte-offsets (all hot-loop ds ops become base + immediate) ----
  const u32 swzw = (u32)((myS & 7) << 4);
  const u32 swzr = (u32)((cl & 7) << 4);
  u32 wo[8];   // L1 write offsets (b64), buf0
#pragma unroll
  for (int nt = 0; nt < 8; ++nt)
    wo[nt] = (u32)(myS * 256) + (((u32)(nt * 32 + kg * 8)) ^ swzw);
  u32 ro[4];   // L2 read offsets (b128) at st=0, buf0
#pragma unroll
  for (int kk = 0; kk < 4; ++kk)
    ro[kk] = (u32)(cl * 256) + (((u32)(kk * 64 + kg * 16)) ^ swzr);
  const u32 po_w = (u32)(cl * 48 + wv * 4);    // part write base (kg==0 lanes)
  const u32 po_r = (u32)(myS * 48 + kg * 16);  // part read base (f32x4)
  const u32 ho = (u32)(kg * 16);               // hcbuf read base (+nt*64 imm)

  // ---------------- prologue ----------------
  if (t < 39) {   // view-dir features: [vd(3), sin(18), cos(18)]
    float val;
    if (t < 3) val = vdirs[r * 3 + t];
    else {
      int jj = t - 3;
      int trig = jj / 18;
      int rem = jj % 18;
      int c = rem / 6, k = rem % 6;
      float v = vdirs[r * 3 + c] * (float)(1 << k);
      val = trig ? cosf(v) : sinf(v);
    }
    featbuf[t] = val;
  }
  // transmittance/weight scan (wave 0, 4 samples/lane)
  if (wv == 0) {
    const float4 dv = *(const float4*)(dens + (size_t)r * 256 + lane * 4);
    const float4 tv = *(const float4*)(dists + (size_t)r * 256 + lane * 4);
    float f[4], al[4];
    float dl[4] = {dv.x, dv.y, dv.z, dv.w};
    float tl[4] = {tv.x, tv.y, tv.z, tv.w};
    float p = 1.0f;
#pragma unroll
    for (int q = 0; q < 4; ++q) {
      float sg = fmaxf(dl[q], 0.0f);
      float e = __expf(-sg * tl[q] * DIST_SCALE);
      al[q] = 1.0f - e;
      f[q] = e + 1e-10f;
      p *= f[q];
    }
    float P = p;
#pragma unroll
    for (int dlt = 1; dlt < 64; dlt <<= 1) {
      float v = __shfl_up(P, dlt, 64);
      if (lane >= dlt) P *= v;
    }
    float E = __shfl_up(P, 1, 64);
    if (lane == 0) E = 1.0f;
    float tr = E;
#pragma unroll
    for (int q = 0; q < 4; ++q) { wbuf[lane * 4 + q] = al[q] * tr; tr *= f[q]; }
  }
  __syncthreads();
  // per-ray folded layer-1 bias: h1c = b1 + vd_feats @ W1[27:66]
  if (t < 128) {
    float s = b1[t];
    for (int j = 0; j < 39; ++j) s += featbuf[j] * W1[(27 + j) * 128 + t];
    hcbuf[t] = s;
  }

  // ---- hoist weights: L1 A-frags for ALL 128 ch (32 VGPR) + L2 slice (32) + W3P (4) ----
  s16x8 w1f[8], w2f[2][4], w3s;
#pragma unroll
  for (int nt = 0; nt < 8; ++nt)
    w1f[nt] = *(const s16x8*)(W1aT + (nt * 16 + cl) * 32 + kg * 8);
#pragma unroll
  for (int nt = 0; nt < 2; ++nt)
#pragma unroll
    for (int kk = 0; kk < 4; ++kk)
      w2f[nt][kk] = *(const s16x8*)(W2T + (chBase + nt * 16 + cl) * 128 + kk * 32 + kg * 8);
  w3s = *(const s16x8*)(W3P + wv * 512 + cl * 32 + kg * 8);

  const f32x4 bb0 = *(const f32x4*)(b2v + chBase + kg * 4);
  const f32x4 bb1 = *(const f32x4*)(b2v + chBase + 16 + kg * 4);
  const float b3c = (kg < 3) ? b3v[kg] : 0.0f;
  float pacc = 0.0f;

  __syncthreads();   // hcbuf ready (read in L1 epilogue every iter)

#pragma unroll
  for (int chunk = 0; chunk < 4; ++chunk) {
    const int HB = (chunk & 1) * 16384;   // one HA buffer = 64*128*2 B = 16384 B

    // ---- layer 1: wave's 16 samples x all 128 ch; B-frag from own prefetched regs ----
    {
      union { u32 u[4]; s16x8 v; } xb;
      xb.u[0] = cvtpk(va[0], va[1]);
      xb.u[1] = cvtpk(va[2], va[3]);
      xb.u[2] = cvtpk(vb[0], vb[1]);
      xb.u[3] = cvtpk(vb[2], vb[3]);   // k>=27 garbage killed by W1aT zero cols
#pragma unroll
      for (int nt = 0; nt < 8; ++nt) {
        f32x4 hcf = *(const f32x4*)(hcB + ho + nt * 64);   // base + imm
        f32x4 a = hcf;
        a = __builtin_amdgcn_mfma_f32_16x16x32_bf16(w1f[nt], xb.v, a, 0, 0, 0);
        u32x2 pk = {cvtpk(fmaxf(a[0], 0.0f), fmaxf(a[1], 0.0f)),
                    cvtpk(fmaxf(a[2], 0.0f), fmaxf(a[3], 0.0f))};
        *(u32x2*)(HAb + wo[nt] + HB) = pk;   // base + imm
      }
    }

    // ---- prefetch next chunk's X into regs (latency spans the barrier + L2 phase) ----
    if (chunk < 3) {
      const float* gp = rayBase + (chunk + 1) * 1728 + myS * 27 + kg * 8;
      if (__builtin_expect(r == 4095 && chunk == 2 && myS == 63 && kg == 3, 0)) {
        va = (f32x4){gp[0], gp[1], gp[2], 0.0f};   // last 3 floats of whole buffer
        vb = (f32x4){0.0f, 0.0f, 0.0f, 0.0f};
      } else {
        va = *(const f32x4*)gp;
        vb = *(const f32x4*)(gp + 4);
      }
    }

    __syncthreads();   // B1: HA[chunk&1] complete; part[(chunk-1)&1] writes visible

    // ---- deferred composite of previous chunk (overlaps other waves' L2 entry) ----
    if (chunk > 0) {
      const float w = wbuf[(chunk - 1) * 64 + myS];
      if (kg < 3) {
        f32x4 pv = *(const f32x4*)(partB + po_r + ((chunk - 1) & 1) * 3072);
        float v = (pv[0] + pv[1]) + (pv[2] + pv[3]) + b3c;
        pacc += w / (1.0f + __expf(-v));
      } else {
        pacc += w;   // acc_map
      }
    }

    // ---- layer 2 (acc init = b2) + fused layer-3 partial (B3-op = own relu'd acc regs) ----
#pragma unroll
    for (int st = 0; st < 4; ++st) {
      s16x8 hbf[4];
#pragma unroll
      for (int kk = 0; kk < 4; ++kk)
        hbf[kk] = *(const s16x8*)(HAb + ro[kk] + HB + st * 4096);   // base + imm
      f32x4 a0 = bb0, a1 = bb1;
#pragma unroll
      for (int kk = 0; kk < 4; ++kk) {
        a0 = __builtin_amdgcn_mfma_f32_16x16x32_bf16(w2f[0][kk], hbf[kk], a0, 0, 0, 0);
        a1 = __builtin_amdgcn_mfma_f32_16x16x32_bf16(w2f[1][kk], hbf[kk], a1, 0, 0, 0);
      }
      union { u32 u[4]; s16x8 v; } b3;
      b3.u[0] = cvtpk(fmaxf(a0[0], 0.0f), fmaxf(a0[1], 0.0f));
      b3.u[1] = cvtpk(fmaxf(a0[2], 0.0f), fmaxf(a0[3], 0.0f));
      b3.u[2] = cvtpk(fmaxf(a1[0], 0.0f), fmaxf(a1[1], 0.0f));
      b3.u[3] = cvtpk(fmaxf(a1[2], 0.0f), fmaxf(a1[3], 0.0f));
      f32x4 p3 = {};
      p3 = __builtin_amdgcn_mfma_f32_16x16x32_bf16(w3s, b3.v, p3, 0, 0, 0);
      if (kg == 0) {   // rgb rows 0..2 -> part[chunk&1][s][c][wv]
        char* pw = partB + po_w + (chunk & 1) * 3072 + st * 768;   // base + imm
        *(float*)(pw) = p3[0];
        *(float*)(pw + 16) = p3[1];
        *(float*)(pw + 32) = p3[2];
      }
    }
    // no trailing barrier: next iter's L1 writes HA[other]; next B1 fences part
  }

  // ---------------- final chunk's composite + reduce ----------------
  __syncthreads();   // part buf1 (chunk 3) writes visible
  {
    const float w = wbuf[3 * 64 + myS];
    if (kg < 3) {
      f32x4 pv = *(const f32x4*)(partB + po_r + 3072);
      float v = (pv[0] + pv[1]) + (pv[2] + pv[3]) + b3c;
      pacc += w / (1.0f + __expf(-v));
    } else {
      pacc += w;
    }
  }
#pragma unroll
  for (int d = 1; d < 16; d <<= 1) pacc += __shfl_xor(pacc, d, 64);
  if (cl == 0) red[wv][kg] = pacc;   // lanes 0,16,32,48: color kg totals of this wave
  __syncthreads();
  if (t == 0) {
    float R = red[0][0] + red[1][0] + red[2][0] + red[3][0];
    float G = red[0][1] + red[1][1] + red[2][1] + red[3][1];
    float B = red[0][2] + red[1][2] + red[2][2] + red[3][2];
    float W = red[0][3] + red[1][3] + red[2][3] + red[3][3];
    float bg = 1.0f - W;
    out[r * 3 + 0] = fminf(fmaxf(R + bg, 0.0f), 1.0f);
    out[r * 3 + 1] = fminf(fmaxf(G + bg, 0.0f), 1.0f);
    out[r * 3 + 2] = fminf(fmaxf(B + bg, 0.0f), 1.0f);
  }
}

extern "C" void kernel_launch(void* const* d_in, const int* in_sizes, int n_in,
                              void* d_out, int out_size, void* d_ws, size_t ws_size,
                              hipStream_t stream) {
  const float* dens = (const float*)d_in[0];
  const float* app  = (const float*)d_in[1];
  const float* vd   = (const float*)d_in[2];
  const float* dist = (const float*)d_in[3];
  const float* W1   = (const float*)d_in[4];
  const float* b1   = (const float*)d_in[5];
  const float* W2   = (const float*)d_in[6];
  const float* b2   = (const float*)d_in[7];
  const float* W3   = (const float*)d_in[8];
  const float* b3   = (const float*)d_in[9];
  unsigned short* wsb = (unsigned short*)d_ws;

  prep_weights<<<32, 256, 0, stream>>>(W1, W2, W3, wsb);
  nerf_main<<<4096, 256, 0, stream>>>(dens, app, vd, dist, W1, b1, b2, b3, wsb, (float*)d_out);
}

// Round 20
// 75.524 us; speedup vs baseline: 1.2492x; 1.0233x over previous
//
#include <hip/hip_runtime.h>
#include <hip/hip_bf16.h>

typedef float f32x4 __attribute__((ext_vector_type(4)));
typedef short s16x8 __attribute__((ext_vector_type(8)));
typedef unsigned int u32;
typedef u32 u32x4 __attribute__((ext_vector_type(4)));

#define DIST_SCALE 25.0f

__device__ __forceinline__ unsigned short f2b(float f) {
  union { float f; unsigned u; } v; v.f = f;
  unsigned r = v.u + 0x7fffu + ((v.u >> 16) & 1u);
  return (unsigned short)(r >> 16);
}

__device__ __forceinline__ u32 cvtpk(float lo, float hi) {
  u32 r;
  asm("v_cvt_pk_bf16_f32 %0, %1, %2" : "=v"(r) : "v"(lo), "v"(hi));
  return r;
}

__global__ void prep_weights(const float* __restrict__ W1, const float* __restrict__ W2,
                             const float* __restrict__ W3, unsigned short* __restrict__ ws) {
  int t = blockIdx.x * 256 + threadIdx.x;
  int stride = gridDim.x * 256;
  // W1aT[n][k] (k padded 27->32 with ZEROS - annihilates X tail garbage)
  for (int i = t; i < 128 * 32; i += stride) {
    int n = i >> 5, k = i & 31;
    ws[i] = (k < 27) ? f2b(W1[k * 128 + n]) : (unsigned short)0;
  }
  // W2Q[n][q]: q-relabeled k-axis so L1's paired-channel b128 writes store H1 in q-order.
  // ch(q) = (2*(q>>5) + ((q>>2)&1))*16 + ((q>>3)&3)*4 + (q&3)
  unsigned short* w2q = ws + 4096;
  for (int i = t; i < 128 * 128; i += stride) {
    int n = i >> 7, q = i & 127;
    int ch = (2 * (q >> 5) + ((q >> 2) & 1)) * 16 + ((q >> 3) & 3) * 4 + (q & 3);
    w2q[i] = f2b(W2[ch * 128 + n]);
  }
  // W3P[wv(4)][n(16)][kslot(32)]: k-slot (kg,j) -> ch = wv*32 + 16*(j>>2) + kg*4 + (j&3)
  unsigned short* w3p = ws + 4096 + 16384;
  for (int i = t; i < 4 * 16 * 32; i += stride) {
    int wv = i >> 9, rem = i & 511, n = rem >> 5, ks = rem & 31;
    int kg = ks >> 3, j = ks & 7;
    int ch = wv * 32 + ((j >> 2) << 4) + kg * 4 + (j & 3);
    w3p[i] = (n < 3) ? f2b(W3[ch * 3 + n]) : (unsigned short)0;
  }
}

__global__ void __launch_bounds__(256) nerf_main(
    const float* __restrict__ dens, const float* __restrict__ app,
    const float* __restrict__ vdirs, const float* __restrict__ dists,
    const float* __restrict__ W1, const float* __restrict__ b1,
    const float* __restrict__ b2v, const float* __restrict__ b3v,
    const unsigned short* __restrict__ wsb, float* __restrict__ out) {
  __shared__ unsigned short HA[2 * 64 * 128];    // 32 KB dbuf H1 (q-order); buf1 at +16384 B
  __shared__ __align__(16) float part[2 * 64 * 12];  // 6 KB C3 partials; buf1 at +3072 B
  __shared__ float wbuf[256];
  __shared__ float hcbuf[128];
  __shared__ float featbuf[40];
  __shared__ float red[4][4];

  const int t = threadIdx.x;
  const int lane = t & 63;
  const int wv = t >> 6;
  const int r = blockIdx.x;

  const unsigned short* W1aT = wsb;
  const unsigned short* W2Q = wsb + 4096;
  const unsigned short* W3P = wsb + 4096 + 16384;
  char* HAb = (char*)HA;
  char* partB = (char*)part;

  const int cl = lane & 15;      // sample-in-tile for L1 C / A-row for L2
  const int kg = lane >> 4;      // k-group
  const int chBase = wv * 32;    // L2: this wave's output-channel slice
  const int myS = wv * 16 + cl;  // L1/composite: this lane's sample within chunk

  const float* rayBase = app + (size_t)r * 6912;

  // ---- prefetch chunk 0 X straight into registers (hidden under prologue) ----
  f32x4 va, vb;
  {
    const float* gp = rayBase + myS * 27 + kg * 8;
    va = *(const f32x4*)gp;
    vb = *(const f32x4*)(gp + 4);
  }

  // ---- hoisted LDS byte-offsets ----
  const u32 swzw = (u32)((myS & 7) << 4);
  const u32 swzr = (u32)((cl & 7) << 4);
  u32 wo4[4];   // L1 paired b128 write offsets, buf0
#pragma unroll
  for (int ntp = 0; ntp < 4; ++ntp)
    wo4[ntp] = (u32)(myS * 256) + (((u32)(ntp * 64 + kg * 16)) ^ swzw);
  u32 ro[4];    // L2 read offsets (b128) at st=0, buf0 (q-order == same addressing)
#pragma unroll
  for (int kk = 0; kk < 4; ++kk)
    ro[kk] = (u32)(cl * 256) + (((u32)(kk * 64 + kg * 16)) ^ swzr);
  const u32 po_w = (u32)(cl * 48 + wv * 4);    // part write base (kg==0 lanes)
  const u32 po_r = (u32)(myS * 48 + kg * 16);  // part read base (f32x4)

  // ---------------- prologue ----------------
  if (t < 39) {   // view-dir features: [vd(3), sin(18), cos(18)]
    float val;
    if (t < 3) val = vdirs[r * 3 + t];
    else {
      int jj = t - 3;
      int trig = jj / 18;
      int rem = jj % 18;
      int c = rem / 6, k = rem % 6;
      float v = vdirs[r * 3 + c] * (float)(1 << k);
      val = trig ? cosf(v) : sinf(v);
    }
    featbuf[t] = val;
  }
  // transmittance/weight scan (wave 0, 4 samples/lane)
  if (wv == 0) {
    const float4 dv = *(const float4*)(dens + (size_t)r * 256 + lane * 4);
    const float4 tv = *(const float4*)(dists + (size_t)r * 256 + lane * 4);
    float f[4], al[4];
    float dl[4] = {dv.x, dv.y, dv.z, dv.w};
    float tl[4] = {tv.x, tv.y, tv.z, tv.w};
    float p = 1.0f;
#pragma unroll
    for (int q = 0; q < 4; ++q) {
      float sg = fmaxf(dl[q], 0.0f);
      float e = __expf(-sg * tl[q] * DIST_SCALE);
      al[q] = 1.0f - e;
      f[q] = e + 1e-10f;
      p *= f[q];
    }
    float P = p;
#pragma unroll
    for (int dlt = 1; dlt < 64; dlt <<= 1) {
      float v = __shfl_up(P, dlt, 64);
      if (lane >= dlt) P *= v;
    }
    float E = __shfl_up(P, 1, 64);
    if (lane == 0) E = 1.0f;
    float tr = E;
#pragma unroll
    for (int q = 0; q < 4; ++q) { wbuf[lane * 4 + q] = al[q] * tr; tr *= f[q]; }
  }
  __syncthreads();
  // per-ray folded layer-1 bias: h1c = b1 + vd_feats @ W1[27:66]
  if (t < 128) {
    float s = b1[t];
    for (int j = 0; j < 39; ++j) s += featbuf[j] * W1[(27 + j) * 128 + t];
    hcbuf[t] = s;
  }

  // ---- hoist weights: L1 A-frags all 128 ch (32 VGPR) + L2 slice (32) + W3P (4) ----
  s16x8 w1f[8], w2f[2][4], w3s;
#pragma unroll
  for (int nt = 0; nt < 8; ++nt)
    w1f[nt] = *(const s16x8*)(W1aT + (nt * 16 + cl) * 32 + kg * 8);
#pragma unroll
  for (int nt = 0; nt < 2; ++nt)
#pragma unroll
    for (int kk = 0; kk < 4; ++kk)
      w2f[nt][kk] = *(const s16x8*)(W2Q + (chBase + nt * 16 + cl) * 128 + kk * 32 + kg * 8);
  w3s = *(const s16x8*)(W3P + wv * 512 + cl * 32 + kg * 8);

  const f32x4 bb0 = *(const f32x4*)(b2v + chBase + kg * 4);
  const f32x4 bb1 = *(const f32x4*)(b2v + chBase + 16 + kg * 4);
  const float b3c = (kg < 3) ? b3v[kg] : 0.0f;
  float pacc = 0.0f;

  __syncthreads();   // hcbuf ready

  // ---- hoist chunk-invariant layer-1 bias C-init into registers (+32 VGPR, -32 DS reads) ----
  f32x4 hcf[8];
#pragma unroll
  for (int nt = 0; nt < 8; ++nt)
    hcf[nt] = *(const f32x4*)(hcbuf + nt * 16 + kg * 4);

#pragma unroll
  for (int chunk = 0; chunk < 4; ++chunk) {
    const int HB = (chunk & 1) * 16384;   // one HA buffer = 64*128*2 B

    // ---- layer 1: 16 samples x 128 ch; paired-channel b128 H1 writes (q-order) ----
    {
      union { u32 u[4]; s16x8 v; } xb;
      xb.u[0] = cvtpk(va[0], va[1]);
      xb.u[1] = cvtpk(va[2], va[3]);
      xb.u[2] = cvtpk(vb[0], vb[1]);
      xb.u[3] = cvtpk(vb[2], vb[3]);   // k>=27 garbage killed by W1aT zero cols
#pragma unroll
      for (int ntp = 0; ntp < 4; ++ntp) {
        f32x4 a0 = hcf[2 * ntp], a1 = hcf[2 * ntp + 1];
        a0 = __builtin_amdgcn_mfma_f32_16x16x32_bf16(w1f[2 * ntp], xb.v, a0, 0, 0, 0);
        a1 = __builtin_amdgcn_mfma_f32_16x16x32_bf16(w1f[2 * ntp + 1], xb.v, a1, 0, 0, 0);
        u32x4 pk = {cvtpk(fmaxf(a0[0], 0.0f), fmaxf(a0[1], 0.0f)),
                    cvtpk(fmaxf(a0[2], 0.0f), fmaxf(a0[3], 0.0f)),
                    cvtpk(fmaxf(a1[0], 0.0f), fmaxf(a1[1], 0.0f)),
                    cvtpk(fmaxf(a1[2], 0.0f), fmaxf(a1[3], 0.0f))};
        *(u32x4*)(HAb + wo4[ntp] + HB) = pk;
      }
    }

    // ---- prefetch next chunk's X into regs (latency spans the barrier + L2 phase) ----
    if (chunk < 3) {
      const float* gp = rayBase + (chunk + 1) * 1728 + myS * 27 + kg * 8;
      if (__builtin_expect(r == 4095 && chunk == 2 && myS == 63 && kg == 3, 0)) {
        va = (f32x4){gp[0], gp[1], gp[2], 0.0f};   // last 3 floats of whole buffer
        vb = (f32x4){0.0f, 0.0f, 0.0f, 0.0f};
      } else {
        va = *(const f32x4*)gp;
        vb = *(const f32x4*)(gp + 4);
      }
    }

    __syncthreads();   // B1: HA[chunk&1] complete; part[(chunk-1)&1] writes visible

    // ---- deferred composite of previous chunk (overlaps other waves' L2 entry) ----
    if (chunk > 0) {
      const float w = wbuf[(chunk - 1) * 64 + myS];
      if (kg < 3) {
        f32x4 pv = *(const f32x4*)(partB + po_r + ((chunk - 1) & 1) * 3072);
        float v = (pv[0] + pv[1]) + (pv[2] + pv[3]) + b3c;
        pacc += w / (1.0f + __expf(-v));
      } else {
        pacc += w;   // acc_map
      }
    }

    // ---- layer 2 (acc init = b2, A = W2Q q-order) + fused layer-3 partial ----
#pragma unroll
    for (int st = 0; st < 4; ++st) {
      s16x8 hbf[4];
#pragma unroll
      for (int kk = 0; kk < 4; ++kk)
        hbf[kk] = *(const s16x8*)(HAb + ro[kk] + HB + st * 4096);   // base + imm
      f32x4 a0 = bb0, a1 = bb1;
      __builtin_amdgcn_s_setprio(1);
#pragma unroll
      for (int kk = 0; kk < 4; ++kk) {
        a0 = __builtin_amdgcn_mfma_f32_16x16x32_bf16(w2f[0][kk], hbf[kk], a0, 0, 0, 0);
        a1 = __builtin_amdgcn_mfma_f32_16x16x32_bf16(w2f[1][kk], hbf[kk], a1, 0, 0, 0);
      }
      __builtin_amdgcn_s_setprio(0);
      union { u32 u[4]; s16x8 v; } b3;
      b3.u[0] = cvtpk(fmaxf(a0[0], 0.0f), fmaxf(a0[1], 0.0f));
      b3.u[1] = cvtpk(fmaxf(a0[2], 0.0f), fmaxf(a0[3], 0.0f));
      b3.u[2] = cvtpk(fmaxf(a1[0], 0.0f), fmaxf(a1[1], 0.0f));
      b3.u[3] = cvtpk(fmaxf(a1[2], 0.0f), fmaxf(a1[3], 0.0f));
      f32x4 p3 = {};
      p3 = __builtin_amdgcn_mfma_f32_16x16x32_bf16(w3s, b3.v, p3, 0, 0, 0);
      if (kg == 0) {   // rgb rows 0..2 -> part[chunk&1][s][c][wv]
        char* pw = partB + po_w + (chunk & 1) * 3072 + st * 768;   // base + imm
        *(float*)(pw) = p3[0];
        *(float*)(pw + 16) = p3[1];
        *(float*)(pw + 32) = p3[2];
      }
    }
    // no trailing barrier: next iter's L1 writes HA[other]; next B1 fences part
  }

  // ---------------- final chunk's composite + reduce ----------------
  __syncthreads();   // part buf1 (chunk 3) writes visible
  {
    const float w = wbuf[3 * 64 + myS];
    if (kg < 3) {
      f32x4 pv = *(const f32x4*)(partB + po_r + 3072);
      float v = (pv[0] + pv[1]) + (pv[2] + pv[3]) + b3c;
      pacc += w / (1.0f + __expf(-v));
    } else {
      pacc += w;
    }
  }
#pragma unroll
  for (int d = 1; d < 16; d <<= 1) pacc += __shfl_xor(pacc, d, 64);
  if (cl == 0) red[wv][kg] = pacc;   // lanes 0,16,32,48: color kg totals of this wave
  __syncthreads();
  if (t == 0) {
    float R = red[0][0] + red[1][0] + red[2][0] + red[3][0];
    float G = red[0][1] + red[1][1] + red[2][1] + red[3][1];
    float B = red[0][2] + red[1][2] + red[2][2] + red[3][2];
    float W = red[0][3] + red[1][3] + red[2][3] + red[3][3];
    float bg = 1.0f - W;
    out[r * 3 + 0] = fminf(fmaxf(R + bg, 0.0f), 1.0f);
    out[r * 3 + 1] = fminf(fmaxf(G + bg, 0.0f), 1.0f);
    out[r * 3 + 2] = fminf(fmaxf(B + bg, 0.0f), 1.0f);
  }
}

extern "C" void kernel_launch(void* const* d_in, const int* in_sizes, int n_in,
                              void* d_out, int out_size, void* d_ws, size_t ws_size,
                              hipStream_t stream) {
  const float* dens = (const float*)d_in[0];
  const float* app  = (const float*)d_in[1];
  const float* vd   = (const float*)d_in[2];
  const float* dist = (const float*)d_in[3];
  const float* W1   = (const float*)d_in[4];
  const float* b1   = (const float*)d_in[5];
  const float* W2   = (const float*)d_in[6];
  const float* b2   = (const float*)d_in[7];
  const float* W3   = (const float*)d_in[8];
  const float* b3   = (const float*)d_in[9];
  unsigned short* wsb = (unsigned short*)d_ws;

  prep_weights<<<32, 256, 0, stream>>>(W1, W2, W3, wsb);
  nerf_main<<<4096, 256, 0, stream>>>(dens, app, vd, dist, W1, b1, b2, b3, wsb, (float*)d_out);
}